// Round 1
// 303.633 us; speedup vs baseline: 1.0130x; 1.0130x over previous
//
#include <hip/hip_runtime.h>
#include <hip/hip_bf16.h>

// Problem constants
#define B_      16
#define Q_      300
#define BQ      (B_*Q_)        // 4800
#define HIDDEN_ 256
#define NHEADS  8
#define PTOT    16             // points per head (4 levels x 4)
#define S_      13294
#define NOFF    256            // total_points*2
#define NATTN   128            // total_points
#define NCOLS   (NOFF+NATTN)   // 384 fused output columns
#define OSTRIDE 388            // o_s row stride (f32): 388%32=4 -> conflict-free epilogue col reads
#define AS      264            // A_s row stride in bf16 (528 B)
#define MROWS   20             // proj rows per block -> grid 240 (<=1 block/CU, no tail round)

typedef __attribute__((ext_vector_type(8))) short bf16x8;   // 8 bf16 (4 VGPRs)
typedef __attribute__((ext_vector_type(4))) float floatx4;  // MFMA C/D

// round-to-nearest-even f32 -> bf16 bits
__device__ __forceinline__ short f2bf(float f) {
    unsigned u = __float_as_uint(f);
    unsigned r = (u + 0x7fffu + ((u >> 16) & 1u)) >> 16;
    return (short)r;
}

// ---------------------------------------------------------------------------
// Kernel 0: build W^T in bf16:  Wt[j][k] = W[:,j][k]   (384 x 256, k-contig)
// Coalesced via 64x64 LDS transpose tile (was: 4B loads at 1KB stride).
// grid = 24 (6 j-tiles x 4 k-tiles), block = 256.
// ---------------------------------------------------------------------------
__global__ __launch_bounds__(256) void prep_kernel(
    const float* __restrict__ W_off,   // (256,256)
    const float* __restrict__ W_attn,  // (256,128)
    short* __restrict__ Wt)            // (384,256) bf16
{
    __shared__ float tile[64][68];     // +4 pad: column reads 2-way (free)

    const int t  = threadIdx.x;
    const int jb = blockIdx.x >> 2;    // 0..5  (j tile)
    const int kb = blockIdx.x & 3;     // 0..3  (k tile)
    const int j0 = jb * 64;
    const int k0 = kb * 64;

    // j-tiles never straddle the W_off / W_attn boundary (256 = 4*64)
    const float* src  = (j0 < NOFF) ? (W_off + j0) : (W_attn + (j0 - NOFF));
    const int   srcld = (j0 < NOFF) ? NOFF : NATTN;

    // Load 64k x 64j tile, coalesced (256B-contig per row-quarter)
    const int jl4 = (t & 15) * 4;
    const int kl  = t >> 4;            // 0..15
    #pragma unroll
    for (int r = 0; r < 4; ++r) {
        const int k = kl + r * 16;
        const float4 v = *(const float4*)(src + (size_t)(k0 + k) * srcld + jl4);
        tile[k][jl4]     = v.x;
        tile[k][jl4 + 1] = v.y;
        tile[k][jl4 + 2] = v.z;
        tile[k][jl4 + 3] = v.w;
    }
    __syncthreads();

    // Transposed read (column jl, stride 68 -> 2-way alias, free), bf16 write
    const int jl = t >> 2;             // 0..63
    const int kq = (t & 3) * 16;       // 0..48
    bf16x8 v0, v1;
    #pragma unroll
    for (int s = 0; s < 8; ++s) v0[s] = f2bf(tile[kq + s][jl]);
    #pragma unroll
    for (int s = 0; s < 8; ++s) v1[s] = f2bf(tile[kq + 8 + s][jl]);
    short* dst = Wt + (size_t)(j0 + jl) * HIDDEN_ + k0 + kq;
    *(bf16x8*)dst       = v0;
    *(bf16x8*)(dst + 8) = v1;
}

// ---------------------------------------------------------------------------
// Kernel A: MFMA projection GEMM (20 rows x 384 cols x K=256 per block)
//           + bias + softmax + location epilogue.
// grid = 240 (exactly <=1 block/CU: no 2-round tail; was 300), block = 512.
// Two 16-row M-tiles (rows 20..31 of A_s are junk; MFMA output rows depend
// only on their own A row, and junk rows are never written out).
// ---------------------------------------------------------------------------
__global__ __launch_bounds__(512) void proj_kernel(
    const float* __restrict__ hidden,   // (4800, 256) f32
    const float* __restrict__ refp,     // (4800, 4)
    const short* __restrict__ Wt,       // (384, 256) bf16, k-contiguous
    const float* __restrict__ b_off,    // (256)
    const float* __restrict__ b_attn,   // (128)
    float* __restrict__ aw_out,         // (4800, 128)
    float* __restrict__ loc_out)        // (4800, 8, 16, 2)
{
    __shared__ short A_s[32 * AS];           // 16.9 KB (rows 20..31 unwritten)
    __shared__ float o_s[MROWS * OSTRIDE];   // 31.0 KB logits

    const int tid  = threadIdx.x;
    const int wave = tid >> 6;              // 0..7
    const int lane = tid & 63;
    const int m    = lane & 15;             // row (A) / col (B/D)
    const int quad = lane >> 4;
    const int row0 = blockIdx.x * MROWS;

    // Stage A as bf16: 320 threads, 16 threads/row x 16 elems each
    if (tid < MROWS * 16) {
        const int r  = tid >> 4;
        const int ks = (tid & 15) * 16;
        const float* hp = hidden + (size_t)(row0 + r) * HIDDEN_ + ks;
        float4 a0 = *(const float4*)hp;
        float4 a1 = *(const float4*)(hp + 4);
        float4 a2 = *(const float4*)(hp + 8);
        float4 a3 = *(const float4*)(hp + 12);
        bf16x8 v0, v1;
        v0[0] = f2bf(a0.x); v0[1] = f2bf(a0.y); v0[2] = f2bf(a0.z); v0[3] = f2bf(a0.w);
        v0[4] = f2bf(a1.x); v0[5] = f2bf(a1.y); v0[6] = f2bf(a1.z); v0[7] = f2bf(a1.w);
        v1[0] = f2bf(a2.x); v1[1] = f2bf(a2.y); v1[2] = f2bf(a2.z); v1[3] = f2bf(a2.w);
        v1[4] = f2bf(a3.x); v1[5] = f2bf(a3.y); v1[6] = f2bf(a3.z); v1[7] = f2bf(a3.w);
        *(bf16x8*)(A_s + r * AS + ks)     = v0;
        *(bf16x8*)(A_s + r * AS + ks + 8) = v1;
    }
    __syncthreads();

    floatx4 acc[2][3];
    #pragma unroll
    for (int mt = 0; mt < 2; ++mt)
        #pragma unroll
        for (int i = 0; i < 3; ++i)
            #pragma unroll
            for (int r = 0; r < 4; ++r) acc[mt][i][r] = 0.f;

    #pragma unroll
    for (int k0 = 0; k0 < HIDDEN_; k0 += 32) {
        const int kk = k0 + quad * 8;
        bf16x8 af0 = *(const bf16x8*)(A_s + m * AS + kk);          // rows 0..15
        bf16x8 af1 = *(const bf16x8*)(A_s + (16 + m) * AS + kk);   // rows 16..19 (+junk)
        #pragma unroll
        for (int i = 0; i < 3; ++i) {
            const int n0 = (wave * 3 + i) * 16;
            bf16x8 bf = *(const bf16x8*)(Wt + (size_t)(n0 + m) * HIDDEN_ + kk);
            acc[0][i] = __builtin_amdgcn_mfma_f32_16x16x32_bf16(af0, bf, acc[0][i], 0, 0, 0);
            acc[1][i] = __builtin_amdgcn_mfma_f32_16x16x32_bf16(af1, bf, acc[1][i], 0, 0, 0);
        }
    }

    // D layout: col = lane&15, row = quad*4 + reg  (measured, m89/m91)
    #pragma unroll
    for (int i = 0; i < 3; ++i) {
        const int n0  = (wave * 3 + i) * 16;
        const int col = n0 + m;
        const float bias = (col < NOFF) ? b_off[col] : b_attn[col - NOFF];
        #pragma unroll
        for (int r = 0; r < 4; ++r) {
            o_s[(quad * 4 + r) * OSTRIDE + col] = acc[0][i][r] + bias;
            if (quad == 0)                       // rows 16..19 only
                o_s[(16 + r) * OSTRIDE + col] = acc[1][i][r] + bias;
        }
    }
    __syncthreads();

    // Epilogue: 160 threads, one per (row, head): softmax + location compute
    if (tid < MROWS * NHEADS) {
        const int r  = tid >> 3;
        const int hd = tid & 7;
        const int row = row0 + r;

        float a[PTOT];
        float mx = -1e30f;
        #pragma unroll
        for (int p = 0; p < PTOT; ++p) {
            a[p] = o_s[r * OSTRIDE + NOFF + hd * PTOT + p];
            mx = fmaxf(mx, a[p]);
        }
        float s = 0.f;
        #pragma unroll
        for (int p = 0; p < PTOT; ++p) { a[p] = __expf(a[p] - mx); s += a[p]; }
        const float inv = 1.f / s;

        const float4 rp = ((const float4*)refp)[row];    // (cx, cy, w, h)
        const float sx = 0.25f * rp.z * 0.5f;            // scale(1/4) * w * OFFSET_SCALE
        const float sy = 0.25f * rp.w * 0.5f;

        #pragma unroll
        for (int p = 0; p < PTOT; ++p) {
            const float awv = a[p] * inv;
            aw_out[row * NATTN + hd * PTOT + p] = awv;
            const float ox = o_s[r * OSTRIDE + (hd * PTOT + p) * 2];
            const float oy = o_s[r * OSTRIDE + (hd * PTOT + p) * 2 + 1];
            ((float2*)loc_out)[(row * NHEADS + hd) * PTOT + p] =
                make_float2(rp.x + ox * sx, rp.y + oy * sy);
        }
    }
}

// ---------------------------------------------------------------------------
// Kernel B: bilinear sampling + weighted sum.
// Phase 1: 512 (g,hd,p) tasks/block computed cooperatively -> LDS holds
//          per-tap {row-offset, weight*aw}.
// Phase 2: 64 taps x {ds_read_b64 (broadcast), dwordx4 gather, 4 FMA}.
// Tap region stride = 65 float2 (was 64): reader bank = (2hd+2i)%32 -> the
// 8 heads of a wave hit 8 distinct banks (was: all 8 on one bank, 8-way).
// XCD-aware swizzle: batch b -> XCD b/2 (enc working set per XCD L2).
// ---------------------------------------------------------------------------
#define TSTRIDE 65
__global__ __launch_bounds__(256) void sample_kernel(
    const float* __restrict__ enc,   // (16, 13294, 256)
    const float* __restrict__ aw,    // (4800, 128)
    const float* __restrict__ loc,   // (4800, 8, 16, 2)
    float* __restrict__ out)         // (4800, 256)
{
    // blockIdx -> (batch, query-block) with XCD locality (bijective on 0..1199)
    const int xcd = blockIdx.x & 7;
    const int idx = blockIdx.x >> 3;             // 0..149
    const int hi  = (idx >= 75);
    const int bb  = xcd * 2 + hi;                // batch 0..15
    const int qb  = idx - hi * 75;               // 0..74
    const int bq0 = bb * Q_ + qb * 4;

    __shared__ float2 tw_s[4 * NHEADS * TSTRIDE];    // 32 regions x 65 entries, 16.6 KB

    const int tid = threadIdx.x;

    // Phase 1: 512 point-tasks, 2 per thread
    for (int t = tid; t < 4 * NHEADS * PTOT; t += 256) {
        const int g    = t >> 7;          // query in block
        const int rest = t & 127;         // hd*16+p
        const int p    = rest & 15;
        const int bq   = bq0 + g;

        const float2 lxy = ((const float2*)loc)[(size_t)bq * NATTN + rest];
        const float  a   = aw[(size_t)bq * NATTN + rest];

        const int lvl   = p >> 2;
        const int Wl    = (lvl == 0) ? 100 : (lvl == 1) ? 50 : (lvl == 2) ? 25 : 13;
        const int start = (lvl == 0) ? 0 : (lvl == 1) ? 10000 : (lvl == 2) ? 12500 : 13125;

        const float x = lxy.x * (float)Wl - 0.5f;
        const float y = lxy.y * (float)Wl - 0.5f;
        const float x0f = floorf(x), y0f = floorf(y);
        const float wx1 = x - x0f, wx0 = 1.f - wx1;
        const float wy1 = y - y0f, wy0 = 1.f - wy1;
        const int x0 = (int)x0f, y0 = (int)y0f;
        const int x1 = x0 + 1,  y1 = y0 + 1;

        const int x0c = x0 < 0 ? 0 : (x0 > Wl-1 ? Wl-1 : x0);
        const int x1c = x1 < 0 ? 0 : (x1 > Wl-1 ? Wl-1 : x1);
        const int y0c = y0 < 0 ? 0 : (y0 > Wl-1 ? Wl-1 : y0);
        const int y1c = y1 < 0 ? 0 : (y1 > Wl-1 ? Wl-1 : y1);
        const bool vx0 = (x0 >= 0) & (x0 <= Wl-1);
        const bool vx1 = (x1 >= 0) & (x1 <= Wl-1);
        const bool vy0 = (y0 >= 0) & (y0 <= Wl-1);
        const bool vy1 = (y1 >= 0) & (y1 <= Wl-1);

        const int r00 = start + y0c * Wl + x0c;
        const int r01 = start + y0c * Wl + x1c;
        const int r10 = start + y1c * Wl + x0c;
        const int r11 = start + y1c * Wl + x1c;

        // region = g*8+hd = t>>4 ; within-region offset p*4
        float2* dst = &tw_s[(t >> 4) * TSTRIDE + (t & 15) * 4];
        dst[0] = make_float2(__int_as_float(r00), (vy0 & vx0) ? a * wy0 * wx0 : 0.f);
        dst[1] = make_float2(__int_as_float(r01), (vy0 & vx1) ? a * wy0 * wx1 : 0.f);
        dst[2] = make_float2(__int_as_float(r10), (vy1 & vx0) ? a * wy1 * wx0 : 0.f);
        dst[3] = make_float2(__int_as_float(r11), (vy1 & vx1) ? a * wy1 * wx1 : 0.f);
    }
    __syncthreads();

    // Phase 2: gather + accumulate
    const int g    = tid >> 6;           // query within block
    const int lane = tid & 63;
    const int hd   = lane >> 3;
    const int cq   = lane & 7;           // float4 index within head
    const int bq   = bq0 + g;

    const float4* encb = (const float4*)(enc + (size_t)bb * S_ * HIDDEN_);
    const int c4   = hd * 8 + cq;        // float4 column within 64-float4 row
    const int base = (g * NHEADS + hd) * TSTRIDE;

    float4 acc = make_float4(0.f, 0.f, 0.f, 0.f);

    #pragma unroll 16
    for (int i = 0; i < PTOT * 4; ++i) {
        const float2 tw = tw_s[base + i];         // broadcast across 8 lanes
        const int row = __float_as_int(tw.x);
        const float w = tw.y;
        const float4 v = encb[(size_t)row * 64 + c4];
        acc.x = fmaf(w, v.x, acc.x);
        acc.y = fmaf(w, v.y, acc.y);
        acc.z = fmaf(w, v.z, acc.z);
        acc.w = fmaf(w, v.w, acc.w);
    }

    ((float4*)out)[(size_t)bq * 64 + c4] = acc;
}

extern "C" void kernel_launch(void* const* d_in, const int* in_sizes, int n_in,
                              void* d_out, int out_size, void* d_ws, size_t ws_size,
                              hipStream_t stream) {
    const float* hidden = (const float*)d_in[0];   // (16,300,256)
    const float* enc    = (const float*)d_in[1];   // (16,13294,256)
    const float* refp   = (const float*)d_in[2];   // (16,300,1,4)
    const float* W_off  = (const float*)d_in[3];   // (256,256)
    const float* b_off  = (const float*)d_in[4];   // (256)
    const float* W_attn = (const float*)d_in[5];   // (256,128)
    const float* b_attn = (const float*)d_in[6];   // (128)

    float* out    = (float*)d_out;                 // (4800,256)
    float* aw_out = out + (size_t)BQ * HIDDEN_;    // (4800,128)

    short* Wt     = (short*)d_ws;                  // 384x256 bf16 = 192 KB
    float* loc_ws = (float*)d_ws + 65536;          // (4800,8,16,2) @ +256 KB

    prep_kernel<<<24, 256, 0, stream>>>(W_off, W_attn, Wt);
    proj_kernel<<<BQ / MROWS, 512, 0, stream>>>(hidden, refp, Wt, b_off, b_attn, aw_out, loc_ws);
    sample_kernel<<<BQ / 4, 256, 0, stream>>>(enc, aw_out, loc_ws, out);
}